// Round 10
// baseline (705.622 us; speedup 1.0000x reference)
//
#include <hip/hip_runtime.h>
#include <math.h>

#define BB 8
#define NN 2048
#define KK 10
#define NLIST 32   // one top-10 key-list per 64-col j-tile
#define EPSF 1e-5f
#define NEG_SLOPE 0.2f

// ---------------- xx[n] = sum_c x[n,c]^2 ----------------
__global__ void xx_kernel(const float* __restrict__ x, float* __restrict__ xx, int C) {
    int i = blockIdx.x * blockDim.x + threadIdx.x;
    if (i >= BB * NN) return;
    const float* row = x + (size_t)i * C;
    float s = 0.f;
    for (int c = 0; c < C; ++c) { float v = row[c]; s = fmaf(v, v, s); }
    xx[i] = s;
}

// ---- per-tile selection: build u64 keys from ds row, Batcher-sort 16,
//      pop-merge 10 across the row's 4 lanes, write sorted top-10 keys ----
// key = (sortable(v)<<32) | ~j : key desc == (v desc, j asc) == top_k order.
__device__ __forceinline__ void tile_select_write(
    float (*ds)[68], int rrow, int seg, unsigned cand_base,
    unsigned long long* __restrict__ pkrow) {
    unsigned njb = ~(cand_base + (unsigned)(seg << 4));   // ~(jb+s) = njb - s
    unsigned long long key[16];
    #pragma unroll
    for (int q = 0; q < 4; ++q) {
        float4 f = *(const float4*)&ds[rrow][(seg << 4) + (q << 2)];
        float fv[4] = {f.x, f.y, f.z, f.w};
        #pragma unroll
        for (int e = 0; e < 4; ++e) {
            unsigned bv = __float_as_uint(fv[e]);
            bv = (bv & 0x80000000u) ? ~bv : (bv | 0x80000000u);
            key[(q << 2) + e] = ((unsigned long long)bv << 32) |
                                (unsigned long long)(njb - (unsigned)((q << 2) + e));
        }
    }
    // Batcher odd-even mergesort, 16 keys desc, 63 CE, fully static
    #pragma unroll
    for (int p = 1; p < 16; p <<= 1)
        #pragma unroll
        for (int k = p; k >= 1; k >>= 1)
            #pragma unroll
            for (int j = k % p; j + k < 16; j += 2 * k)
                #pragma unroll
                for (int i = 0; i < k; ++i)
                    if ((i + j) / (2 * p) == (i + j + k) / (2 * p)) {
                        unsigned long long ka = key[i + j], kb = key[i + j + k];
                        bool sw = kb > ka;
                        key[i + j] = sw ? kb : ka;
                        key[i + j + k] = sw ? ka : kb;
                    }
    // pop-merge across the 4 lanes of this row (shift depth 9: lane pops <=10)
    #pragma unroll 1
    for (int r = 0; r < KK; ++r) {
        unsigned long long h = key[0];
        unsigned long long o = __shfl_xor(h, 1);
        if (o > h) h = o;
        o = __shfl_xor(h, 2);
        if (o > h) h = o;
        if (seg == 0) pkrow[r] = h;
        if (key[0] == h) {   // keys globally distinct: exactly one lane pops
            #pragma unroll
            for (int s = 0; s < KK - 1; ++s) key[s] = key[s + 1];
            key[KK - 1] = 0;   // sentinel
        }
    }
}

// ---------------- fused dist GEMM + top-10, symmetric tiles ----------------
// One block per triangular tile pair (ti<=tj): 528 pairs x 8 batches.
// GEMM computed once; pass 1 emits (rows i0, cands tj); off-diagonal blocks
// restage transposed (mirrored transform, reference subtraction order) and
// emit (rows j0, cands ti).
// ASYNC-STAGE (R10): chunk k+1's global loads are ISSUED right after the
// staging barrier, before chunk k's FMAs -- HBM/L2 latency hides under the
// FMA phase instead of sitting on the barrier chain. Evidence: dur was flat
// across C=64/128 despite 2x FMAs -> latency/barrier-bound, not VALU-bound.
// Values staged, FMA chain (k-ascending), transform: all bit-identical.
// DO NOT add launch_bounds waves hints: (256,8)->VGPR32, (256,6)->VGPR40,
// both spilled GBs to scratch. Natural allocation only. VGPR watch: +16 for
// prefetch regs (36 -> ~52); must stay <= 64 for 8 waves/SIMD.
template<int C>
__global__ __launch_bounds__(256) void dist_topk_kernel(
    const float* __restrict__ x, const float* __restrict__ xx,
    unsigned long long* __restrict__ pk) {
    constexpr int KC = (C >= 32) ? 32 : 16;
    constexpr int NKC = (C + KC - 1) / KC;             // 5->1, 64->2, 128->4
    __shared__ float smem[4352];                       // 17408 B union
    float (*As)[68] = (float(*)[68])smem;              // [KC][68]
    float (*Bs)[68] = (float(*)[68])(smem + KC * 68);  // [KC][68]
    float (*ds)[68] = (float(*)[68])smem;              // [64][68] aliases
    // triangular decode: blockIdx.x -> (ti, tj), ti <= tj
    int t = blockIdx.x;
    int ti = 0;
    #pragma unroll 1
    while (t >= 32 - ti) { t -= 32 - ti; ++ti; }
    int tj = ti + t;
    int b = blockIdx.y;
    int i0 = ti << 6, j0 = tj << 6;
    const float* xb = x + (size_t)b * NN * C;
    const float* xxb = xx + (size_t)b * NN;
    int tid = threadIdx.x;
    int tx = tid & 15, ty = tid >> 4;
    int vr = tid & 63, vq = tid >> 6;

    float acc[4][4] = {};
    if constexpr (C >= 32) {
        // prologue: chunk 0 -> regs
        float4 ra0 = *(const float4*)&xb[(i0 + vr) * C + (vq << 2)];
        float4 rb0 = *(const float4*)&xb[(j0 + vr) * C + (vq << 2)];
        float4 ra1 = *(const float4*)&xb[(i0 + vr) * C + 16 + (vq << 2)];
        float4 rb1 = *(const float4*)&xb[(j0 + vr) * C + 16 + (vq << 2)];
        #pragma unroll 1
        for (int kc = 0; kc < NKC; ++kc) {
            int c0 = vq << 2;
            As[c0 + 0][vr] = ra0.x; As[c0 + 1][vr] = ra0.y;
            As[c0 + 2][vr] = ra0.z; As[c0 + 3][vr] = ra0.w;
            As[c0 + 16][vr] = ra1.x; As[c0 + 17][vr] = ra1.y;
            As[c0 + 18][vr] = ra1.z; As[c0 + 19][vr] = ra1.w;
            Bs[c0 + 0][vr] = rb0.x; Bs[c0 + 1][vr] = rb0.y;
            Bs[c0 + 2][vr] = rb0.z; Bs[c0 + 3][vr] = rb0.w;
            Bs[c0 + 16][vr] = rb1.x; Bs[c0 + 17][vr] = rb1.y;
            Bs[c0 + 18][vr] = rb1.z; Bs[c0 + 19][vr] = rb1.w;
            __syncthreads();
            if (kc + 1 < NKC) {   // issue next chunk's loads BEFORE the FMAs
                int k0 = (kc + 1) * KC;
                ra0 = *(const float4*)&xb[(i0 + vr) * C + k0 + (vq << 2)];
                rb0 = *(const float4*)&xb[(j0 + vr) * C + k0 + (vq << 2)];
                ra1 = *(const float4*)&xb[(i0 + vr) * C + k0 + 16 + (vq << 2)];
                rb1 = *(const float4*)&xb[(j0 + vr) * C + k0 + 16 + (vq << 2)];
            }
            #pragma unroll
            for (int kk = 0; kk < KC; ++kk) {
                float4 a4 = *(const float4*)&As[kk][ty << 2];
                float4 b4 = *(const float4*)&Bs[kk][tx << 2];
                float a[4] = {a4.x, a4.y, a4.z, a4.w};
                float bv[4] = {b4.x, b4.y, b4.z, b4.w};
                #pragma unroll
                for (int u = 0; u < 4; ++u)
                    #pragma unroll
                    for (int v = 0; v < 4; ++v)
                        acc[u][v] = fmaf(a[u], bv[v], acc[u][v]);
            }
            __syncthreads();
        }
    } else {
        // C=5: single chunk, scalar staging, bit-identical zero padding
        #pragma unroll
        for (int l = tid; l < KC * 64; l += 256) {
            int r = l >> 4, c = l & 15;
            As[c][r] = (c < C) ? xb[(i0 + r) * C + c] : 0.f;
            Bs[c][r] = (c < C) ? xb[(j0 + r) * C + c] : 0.f;
        }
        __syncthreads();
        #pragma unroll
        for (int kk = 0; kk < KC; ++kk) {
            float4 a4 = *(const float4*)&As[kk][ty << 2];
            float4 b4 = *(const float4*)&Bs[kk][tx << 2];
            float a[4] = {a4.x, a4.y, a4.z, a4.w};
            float bv[4] = {b4.x, b4.y, b4.z, b4.w};
            #pragma unroll
            for (int u = 0; u < 4; ++u)
                #pragma unroll
                for (int v = 0; v < 4; ++v)
                    acc[u][v] = fmaf(a[u], bv[v], acc[u][v]);
        }
        __syncthreads();
    }

    int rrow = tid >> 2, seg = tid & 3;

    // ---- pass 1: rows = i0 block, candidates = tile tj ----
    {
        float4 xi4 = *(const float4*)&xxb[i0 + (ty << 2)];
        float xi[4] = {xi4.x, xi4.y, xi4.z, xi4.w};
        float4 xj4 = *(const float4*)&xxb[j0 + (tx << 2)];
        float xj[4] = {xj4.x, xj4.y, xj4.z, xj4.w};
        #pragma unroll
        for (int u = 0; u < 4; ++u) {
            float4 o;
            o.x = 2.f * acc[u][0] - xi[u] - xj[0];
            o.y = 2.f * acc[u][1] - xi[u] - xj[1];
            o.z = 2.f * acc[u][2] - xi[u] - xj[2];
            o.w = 2.f * acc[u][3] - xi[u] - xj[3];
            *(float4*)&ds[(ty << 2) + u][tx << 2] = o;
        }
        __syncthreads();
        size_t prow = ((size_t)tj * (BB * NN)) + (size_t)b * NN + i0 + rrow;
        tile_select_write(ds, rrow, seg, (unsigned)j0, pk + prow * KK);
    }

    // ---- pass 2 (off-diagonal): rows = j0 block, candidates = tile ti ----
    if (ti != tj) {
        __syncthreads();   // all pass-1 ds reads done before overwrite
        float4 xi4 = *(const float4*)&xxb[i0 + (ty << 2)];   // reload (L2 hit)
        float xi[4] = {xi4.x, xi4.y, xi4.z, xi4.w};
        float4 xj4 = *(const float4*)&xxb[j0 + (tx << 2)];
        float xj[4] = {xj4.x, xj4.y, xj4.z, xj4.w};
        // transposed stage: row (tx*4+v) = point j0+tx*4+v, cols = i0 block.
        #pragma unroll
        for (int v = 0; v < 4; ++v) {
            float4 o;
            o.x = 2.f * acc[0][v] - xj[v] - xi[0];
            o.y = 2.f * acc[1][v] - xj[v] - xi[1];
            o.z = 2.f * acc[2][v] - xj[v] - xi[2];
            o.w = 2.f * acc[3][v] - xj[v] - xi[3];
            *(float4*)&ds[(tx << 2) + v][ty << 2] = o;
        }
        __syncthreads();
        size_t prow = ((size_t)ti * (BB * NN)) + (size_t)b * NN + j0 + rrow;
        tile_select_write(ds, rrow, seg, (unsigned)i0, pk + prow * KK);
    }
}

// ---------------- wave-parallel merge of NLIST sorted key-lists ----------------
// 2 rows per wave: lanes 0-31 = row A's 32 list heads, lanes 32-63 = row B.
__global__ __launch_bounds__(256) void topk_merge_kernel(
    const unsigned long long* __restrict__ pk, int* __restrict__ idxout) {
    int wid = threadIdx.x >> 6, lane = threadIdx.x & 63;
    int half = lane >> 5, l = lane & 31;
    int row = (blockIdx.x << 3) + (wid << 1) + half;
    size_t base = ((size_t)l * (BB * NN) + row) * KK;
    unsigned long long key = pk[base];
    int p = 0;
    int* out = idxout + (size_t)row * KK;
    for (int r = 0; r < KK; ++r) {
        unsigned long long h = key, o;
        o = __shfl_xor(h, 16); if (o > h) h = o;
        o = __shfl_xor(h, 8);  if (o > h) h = o;
        o = __shfl_xor(h, 4);  if (o > h) h = o;
        o = __shfl_xor(h, 2);  if (o > h) h = o;
        o = __shfl_xor(h, 1);  if (o > h) h = o;
        if (l == 0) out[r] = (int)(~(unsigned)h);
        if (key == h) {
            ++p;
            key = (p < KK) ? pk[base + p] : 0ull;
        }
    }
}

// ---------------- y,z = X*W1^T, X*W2^T as one tiled GEMM ----------------
// Same async-stage pattern as dist: chunk k+1 loads issued before chunk k's
// FMAs. Staged values / FMA order bit-identical to previous rounds.
__global__ __launch_bounds__(256) void yz_gemm_kernel(
    const float* __restrict__ x, const float* __restrict__ w,
    float* __restrict__ y, float* __restrict__ z, int C, int co) {
    int n0 = blockIdx.y << 6;     // point tile
    int oc0 = blockIdx.x << 6;    // combined output-channel tile
    __shared__ float As[16][68], Bs[16][68];
    int tid = threadIdx.x;
    int tx = tid & 15, ty = tid >> 4;
    float acc[4][4] = {};
    float ra[4], rb[4];
    #pragma unroll
    for (int t = 0; t < 4; ++t) {          // prologue: chunk 0 -> regs
        int l = tid + (t << 8);
        int r = l >> 4, c = l & 15;
        ra[t] = (c < C) ? x[(size_t)(n0 + r) * C + c] : 0.f;
        float bvv = 0.f;
        if (c < C) {
            int oc = oc0 + r;
            int wrow = (oc < co) ? oc : (oc - co);
            int wcol = (oc < co) ? c : (C + c);
            bvv = w[(size_t)wrow * 2 * C + wcol];
        }
        rb[t] = bvv;
    }
    for (int k0 = 0; k0 < C; k0 += 16) {
        #pragma unroll
        for (int t = 0; t < 4; ++t) {
            int l = tid + (t << 8);
            As[l & 15][l >> 4] = ra[t];
            Bs[l & 15][l >> 4] = rb[t];
        }
        __syncthreads();
        if (k0 + 16 < C) {   // issue next chunk's loads BEFORE the FMAs
            #pragma unroll
            for (int t = 0; t < 4; ++t) {
                int l = tid + (t << 8);
                int r = l >> 4, c = l & 15;
                int kc = k0 + 16 + c;
                ra[t] = (kc < C) ? x[(size_t)(n0 + r) * C + kc] : 0.f;
                float bvv = 0.f;
                if (kc < C) {
                    int oc = oc0 + r;
                    int wrow = (oc < co) ? oc : (oc - co);
                    int wcol = (oc < co) ? kc : (C + kc);
                    bvv = w[(size_t)wrow * 2 * C + wcol];
                }
                rb[t] = bvv;
            }
        }
        #pragma unroll
        for (int kk = 0; kk < 16; ++kk) {
            float4 a4 = *(const float4*)&As[kk][ty << 2];
            float4 b4 = *(const float4*)&Bs[kk][tx << 2];
            float a[4] = {a4.x, a4.y, a4.z, a4.w};
            float bv[4] = {b4.x, b4.y, b4.z, b4.w};
            #pragma unroll
            for (int u = 0; u < 4; ++u)
                #pragma unroll
                for (int v = 0; v < 4; ++v)
                    acc[u][v] = fmaf(a[u], bv[v], acc[u][v]);
        }
        __syncthreads();
    }
    bool isY = (oc0 < co);
    float* dst = isY ? y : z;
    int c0 = isY ? oc0 : (oc0 - co);
    #pragma unroll
    for (int u = 0; u < 4; ++u) {
        int n = n0 + (ty << 2) + u;
        float4 o;
        o.x = acc[u][0]; o.y = acc[u][1]; o.z = acc[u][2]; o.w = acc[u][3];
        *(float4*)&dst[(size_t)n * co + c0 + (tx << 2)] = o;
    }
}

// ---------------- gather + max_k + BN + lrelu ----------------
__global__ void edge_apply_kernel(const float* __restrict__ y, const float* __restrict__ z,
    const int* __restrict__ idx, const float* __restrict__ g, const float* __restrict__ be,
    const float* __restrict__ rm, const float* __restrict__ rv,
    float* __restrict__ out, int co) {
    int n = blockIdx.x;   // global point id in [0, B*N)
    int o = threadIdx.x;
    int b = n >> 11;      // N = 2048
    __shared__ int sj[KK];
    if (o < KK) sj[o] = idx[(size_t)n * KK + o];
    __syncthreads();
    float yn = y[(size_t)n * co + o], zn = z[(size_t)n * co + o];
    float mx = -INFINITY, mn = INFINITY;
    #pragma unroll
    for (int j = 0; j < KK; ++j) {
        float v = y[((size_t)b * NN + sj[j]) * co + o];
        mx = fmaxf(mx, v);
        mn = fminf(mn, v);
    }
    float s = g[o] * rsqrtf(rv[o] + EPSF);
    float tt = be[o] - rm[o] * s;
    float ybest = (s >= 0.f) ? mx : mn;
    float h = fmaf(s, ybest - yn + zn, tt);
    out[(size_t)n * co + o] = (h >= 0.f) ? h : NEG_SLOPE * h;
}

// ---------------- global max over N of concat(x1..x4) ----------------
#define NSPLIT 32
__global__ void gmax_partial(const float* __restrict__ x1, const float* __restrict__ x2,
                             const float* __restrict__ x3, const float* __restrict__ x4,
                             float* __restrict__ part) {
    int ch = threadIdx.x;            // 0..511
    int split = blockIdx.x, b = blockIdx.y;
    int n0 = split * (NN / NSPLIT);
    float m = -INFINITY;
    for (int q = 0; q < NN / NSPLIT; ++q) {
        int n = b * NN + n0 + q;
        float v;
        if (ch < 64)       v = x1[(size_t)n * 64 + ch];
        else if (ch < 128) v = x2[(size_t)n * 64 + (ch - 64)];
        else if (ch < 256) v = x3[(size_t)n * 128 + (ch - 128)];
        else               v = x4[(size_t)n * 256 + (ch - 256)];
        m = fmaxf(m, v);
    }
    part[((size_t)split * BB + b) * 512 + ch] = m;
}

__global__ void gmax_final(const float* __restrict__ part, float* __restrict__ xg) {
    int ch = threadIdx.x, b = blockIdx.x;
    float m = -INFINITY;
    for (int s = 0; s < NSPLIT; ++s) m = fmaxf(m, part[((size_t)s * BB + b) * 512 + ch]);
    xg[(size_t)b * 512 + ch] = m;
}

// ---------------- final linear + BN + lrelu ----------------
__global__ void linear_kernel(const float* __restrict__ xg, const float* __restrict__ lw,
    const float* __restrict__ lb, const float* __restrict__ g5, const float* __restrict__ b5,
    const float* __restrict__ rm5, const float* __restrict__ rv5, float* __restrict__ out0) {
    int o = blockIdx.x * 256 + threadIdx.x;
    int b = blockIdx.y;
    __shared__ float xs[512];
    for (int l = threadIdx.x; l < 512; l += 256) xs[l] = xg[(size_t)b * 512 + l];
    __syncthreads();
    float acc = 0.f;
    const float* wr = lw + (size_t)o * 512;
    for (int c = 0; c < 512; ++c) acc = fmaf(xs[c], wr[c], acc);
    acc += lb[o];
    float s = g5[o] * rsqrtf(rv5[o] + EPSF);
    float h = fmaf(s, acc - rm5[o], b5[o]);
    out0[(size_t)b * 1024 + o] = (h >= 0.f) ? h : NEG_SLOPE * h;
}

// ---------------- x4 (B,N,256) -> out1 (B,256,N) ----------------
__global__ void transpose_kernel(const float* __restrict__ x4, float* __restrict__ out1) {
    __shared__ float tile[32][33];
    int b = blockIdx.z;
    int nb = blockIdx.x * 32, ob = blockIdx.y * 32;
    int tx = threadIdx.x, ty = threadIdx.y;  // (32, 8)
    #pragma unroll
    for (int r = 0; r < 4; ++r) {
        int o = ob + tx;
        int n = nb + ty + r * 8;
        tile[ty + r * 8][tx] = x4[((size_t)b * NN + n) * 256 + o];
    }
    __syncthreads();
    #pragma unroll
    for (int r = 0; r < 4; ++r) {
        int n = nb + tx;
        int o = ob + ty + r * 8;
        out1[((size_t)b * 256 + o) * NN + n] = tile[tx][ty + r * 8];
    }
}

extern "C" void kernel_launch(void* const* d_in, const int* in_sizes, int n_in,
                              void* d_out, int out_size, void* d_ws, size_t ws_size,
                              hipStream_t stream) {
    const float* x = (const float*)d_in[0];
    const float* lin_w = (const float*)d_in[21];
    const float* lin_b = (const float*)d_in[22];
    const float* g5 = (const float*)d_in[23];
    const float* b5 = (const float*)d_in[24];
    const float* rm5 = (const float*)d_in[25];
    const float* rv5 = (const float*)d_in[26];

    // ---- workspace bump allocation ----
    size_t off = 0;
    auto alloc = [&](size_t nbytes) {
        void* r = (char*)d_ws + off;
        off += (nbytes + 255) & ~(size_t)255;
        return r;
    };
    const size_t PTS = (size_t)BB * NN;
    float* xx   = (float*)alloc(PTS * 4);
    int*   idx  = (int*)  alloc(PTS * KK * 4);
    float* y    = (float*)alloc(PTS * 256 * 4);
    float* z    = (float*)alloc(PTS * 256 * 4);
    float* x1   = (float*)alloc(PTS * 64 * 4);
    float* x2   = (float*)alloc(PTS * 64 * 4);
    float* x3   = (float*)alloc(PTS * 128 * 4);
    float* x4   = (float*)alloc(PTS * 256 * 4);
    float* part = (float*)alloc((size_t)NSPLIT * BB * 512 * 4);
    float* xg   = (float*)alloc((size_t)BB * 512 * 4);
    unsigned long long* pk =
        (unsigned long long*)alloc((size_t)NLIST * PTS * KK * 8);  // per-tile top-10 keys

    const int CI[4] = {5, 64, 64, 128};
    const int CO[4] = {64, 64, 128, 256};
    const float* xin = x;
    float* xout[4] = {x1, x2, x3, x4};

    for (int l = 0; l < 4; ++l) {
        int C = CI[l], co = CO[l];
        const float* w  = (const float*)d_in[1 + l * 5 + 0];
        const float* g  = (const float*)d_in[1 + l * 5 + 1];
        const float* be = (const float*)d_in[1 + l * 5 + 2];
        const float* rm = (const float*)d_in[1 + l * 5 + 3];
        const float* rv = (const float*)d_in[1 + l * 5 + 4];

        xx_kernel<<<(BB * NN + 255) / 256, 256, 0, stream>>>(xin, xx, C);

        dim3 dgrid(528, BB);   // triangular tile pairs x batches
        if (C == 5)
            dist_topk_kernel<5><<<dgrid, 256, 0, stream>>>(xin, xx, pk);
        else if (C == 64)
            dist_topk_kernel<64><<<dgrid, 256, 0, stream>>>(xin, xx, pk);
        else
            dist_topk_kernel<128><<<dgrid, 256, 0, stream>>>(xin, xx, pk);
        topk_merge_kernel<<<(int)(PTS / 8), 256, 0, stream>>>(pk, idx);

        yz_gemm_kernel<<<dim3(2 * co / 64, (int)(PTS / 64)), 256, 0, stream>>>(
            xin, w, y, z, C, co);
        edge_apply_kernel<<<(int)PTS, co, 0, stream>>>(y, z, idx, g, be, rm, rv, xout[l], co);
        xin = xout[l];
    }

    gmax_partial<<<dim3(NSPLIT, BB), 512, 0, stream>>>(x1, x2, x3, x4, part);
    gmax_final<<<BB, 512, 0, stream>>>(part, xg);
    linear_kernel<<<dim3(1024 / 256, BB), 256, 0, stream>>>(
        xg, lin_w, lin_b, g5, b5, rm5, rv5, (float*)d_out);
    transpose_kernel<<<dim3(NN / 32, 256 / 32, BB), dim3(32, 8), 0, stream>>>(
        x4, (float*)d_out + (size_t)BB * 1024);
}

// Round 11
// 631.034 us; speedup vs baseline: 1.1182x; 1.1182x over previous
//
#include <hip/hip_runtime.h>
#include <math.h>

#define BB 8
#define NN 2048
#define KK 10
#define NLIST 32   // one top-10 key-list per 64-col j-tile
#define DIST_BLOCKS (528 * BB)
#define EPSF 1e-5f
#define NEG_SLOPE 0.2f

// ---------------- xx[n] = sum_c x[n,c]^2 ----------------
__global__ void xx_kernel(const float* __restrict__ x, float* __restrict__ xx, int C) {
    int i = blockIdx.x * blockDim.x + threadIdx.x;
    if (i >= BB * NN) return;
    const float* row = x + (size_t)i * C;
    float s = 0.f;
    for (int c = 0; c < C; ++c) { float v = row[c]; s = fmaf(v, v, s); }
    xx[i] = s;
}

// ---- per-tile selection: build u64 keys from ds row, Batcher-sort 16,
//      pop-merge 10 across the row's 4 lanes, write sorted top-10 keys ----
// key = (sortable(v)<<32) | ~j : key desc == (v desc, j asc) == top_k order.
__device__ __forceinline__ void tile_select_write(
    float (*ds)[68], int rrow, int seg, unsigned cand_base,
    unsigned long long* __restrict__ pkrow) {
    unsigned njb = ~(cand_base + (unsigned)(seg << 4));   // ~(jb+s) = njb - s
    unsigned long long key[16];
    #pragma unroll
    for (int q = 0; q < 4; ++q) {
        float4 f = *(const float4*)&ds[rrow][(seg << 4) + (q << 2)];
        float fv[4] = {f.x, f.y, f.z, f.w};
        #pragma unroll
        for (int e = 0; e < 4; ++e) {
            unsigned bv = __float_as_uint(fv[e]);
            bv = (bv & 0x80000000u) ? ~bv : (bv | 0x80000000u);
            key[(q << 2) + e] = ((unsigned long long)bv << 32) |
                                (unsigned long long)(njb - (unsigned)((q << 2) + e));
        }
    }
    // Batcher odd-even mergesort, 16 keys desc, 63 CE, fully static
    #pragma unroll
    for (int p = 1; p < 16; p <<= 1)
        #pragma unroll
        for (int k = p; k >= 1; k >>= 1)
            #pragma unroll
            for (int j = k % p; j + k < 16; j += 2 * k)
                #pragma unroll
                for (int i = 0; i < k; ++i)
                    if ((i + j) / (2 * p) == (i + j + k) / (2 * p)) {
                        unsigned long long ka = key[i + j], kb = key[i + j + k];
                        bool sw = kb > ka;
                        key[i + j] = sw ? kb : ka;
                        key[i + j + k] = sw ? ka : kb;
                    }
    // pop-merge across the 4 lanes of this row (shift depth 9: lane pops <=10)
    #pragma unroll 1
    for (int r = 0; r < KK; ++r) {
        unsigned long long h = key[0];
        unsigned long long o = __shfl_xor(h, 1);
        if (o > h) h = o;
        o = __shfl_xor(h, 2);
        if (o > h) h = o;
        if (seg == 0) pkrow[r] = h;
        if (key[0] == h) {   // keys globally distinct: exactly one lane pops
            #pragma unroll
            for (int s = 0; s < KK - 1; ++s) key[s] = key[s + 1];
            key[KK - 1] = 0;   // sentinel
        }
    }
}

// ---------------- FAT KERNEL: dist+topk blocks AND yz GEMM blocks ----------------
// blockIdx.x < DIST_BLOCKS: symmetric dist tile pair (R9 code, verbatim).
// blockIdx.x >= DIST_BLOCKS: one 64x64 yz output tile (R9 yz code, verbatim).
// Rationale (R11): yz depends only on xin, but a single stream serializes it
// behind dist; multi-stream/events are forbidden under graph capture. Fusing
// the two INDEPENDENT grids into one dispatch lets yz blocks fill dist's
// occupancy gaps (dist ran at 45-57% with a 2-fill grid + tail). Disjoint
// outputs, shared read-only inputs -> pure scheduling change, zero numerics.
// Dist blocks first: they are the long pole.
// R10 lesson: async reg-prefetch REGRESSED (VGPR 36->48, occupancy 57->45,
// dist 116->118) -- compiler already schedules staging loads well; do not
// hold loads in registers across barriers. R9 plain staging restored.
// DO NOT add launch_bounds waves hints: (256,8)->VGPR32, (256,6)->VGPR40,
// both spilled GBs to scratch. Natural allocation only.
template<int C>
__global__ __launch_bounds__(256) void dist_yz_kernel(
    const float* __restrict__ x, const float* __restrict__ xx,
    unsigned long long* __restrict__ pk,
    const float* __restrict__ w, float* __restrict__ y, float* __restrict__ z,
    int co) {
    constexpr int KC = (C >= 32) ? 32 : 16;
    __shared__ float smem[4352];                       // 17408 B union
    int tid = threadIdx.x;
    int tx = tid & 15, ty = tid >> 4;

    if (blockIdx.x < DIST_BLOCKS) {
        // ================= dist + top-10 path (R9 verbatim) =================
        float (*As)[68] = (float(*)[68])smem;              // [KC][68]
        float (*Bs)[68] = (float(*)[68])(smem + KC * 68);  // [KC][68]
        float (*ds)[68] = (float(*)[68])smem;              // [64][68] aliases
        int t = blockIdx.x % 528;
        int b = blockIdx.x / 528;
        int ti = 0;
        #pragma unroll 1
        while (t >= 32 - ti) { t -= 32 - ti; ++ti; }
        int tj = ti + t;
        int i0 = ti << 6, j0 = tj << 6;
        const float* xb = x + (size_t)b * NN * C;
        const float* xxb = xx + (size_t)b * NN;
        int vr = tid & 63, vq = tid >> 6;

        float acc[4][4] = {};
        #pragma unroll 1
        for (int k0 = 0; k0 < C; k0 += KC) {
            if constexpr (C >= 32) {
                const float4 a0 = *(const float4*)&xb[(i0 + vr) * C + k0 + (vq << 2)];
                const float4 b0 = *(const float4*)&xb[(j0 + vr) * C + k0 + (vq << 2)];
                const float4 a1 = *(const float4*)&xb[(i0 + vr) * C + k0 + 16 + (vq << 2)];
                const float4 b1 = *(const float4*)&xb[(j0 + vr) * C + k0 + 16 + (vq << 2)];
                int c0 = vq << 2;
                As[c0 + 0][vr] = a0.x; As[c0 + 1][vr] = a0.y;
                As[c0 + 2][vr] = a0.z; As[c0 + 3][vr] = a0.w;
                As[c0 + 16][vr] = a1.x; As[c0 + 17][vr] = a1.y;
                As[c0 + 18][vr] = a1.z; As[c0 + 19][vr] = a1.w;
                Bs[c0 + 0][vr] = b0.x; Bs[c0 + 1][vr] = b0.y;
                Bs[c0 + 2][vr] = b0.z; Bs[c0 + 3][vr] = b0.w;
                Bs[c0 + 16][vr] = b1.x; Bs[c0 + 17][vr] = b1.y;
                Bs[c0 + 18][vr] = b1.z; Bs[c0 + 19][vr] = b1.w;
            } else {
                #pragma unroll
                for (int l = tid; l < KC * 64; l += 256) {
                    int r = l >> 4, c = l & 15;
                    int kc = k0 + c;
                    As[c][r] = (kc < C) ? xb[(i0 + r) * C + kc] : 0.f;
                    Bs[c][r] = (kc < C) ? xb[(j0 + r) * C + kc] : 0.f;
                }
            }
            __syncthreads();
            #pragma unroll
            for (int kk = 0; kk < KC; ++kk) {
                float4 a4 = *(const float4*)&As[kk][ty << 2];
                float4 b4 = *(const float4*)&Bs[kk][tx << 2];
                float a[4] = {a4.x, a4.y, a4.z, a4.w};
                float bv[4] = {b4.x, b4.y, b4.z, b4.w};
                #pragma unroll
                for (int u = 0; u < 4; ++u)
                    #pragma unroll
                    for (int v = 0; v < 4; ++v)
                        acc[u][v] = fmaf(a[u], bv[v], acc[u][v]);
            }
            __syncthreads();
        }

        int rrow = tid >> 2, seg = tid & 3;

        // ---- pass 1: rows = i0 block, candidates = tile tj ----
        {
            float4 xi4 = *(const float4*)&xxb[i0 + (ty << 2)];
            float xi[4] = {xi4.x, xi4.y, xi4.z, xi4.w};
            float4 xj4 = *(const float4*)&xxb[j0 + (tx << 2)];
            float xj[4] = {xj4.x, xj4.y, xj4.z, xj4.w};
            #pragma unroll
            for (int u = 0; u < 4; ++u) {
                float4 o;
                o.x = 2.f * acc[u][0] - xi[u] - xj[0];
                o.y = 2.f * acc[u][1] - xi[u] - xj[1];
                o.z = 2.f * acc[u][2] - xi[u] - xj[2];
                o.w = 2.f * acc[u][3] - xi[u] - xj[3];
                *(float4*)&ds[(ty << 2) + u][tx << 2] = o;
            }
            __syncthreads();
            size_t prow = ((size_t)tj * (BB * NN)) + (size_t)b * NN + i0 + rrow;
            tile_select_write(ds, rrow, seg, (unsigned)j0, pk + prow * KK);
        }

        // ---- pass 2 (off-diagonal): rows = j0 block, candidates = tile ti ----
        if (ti != tj) {
            __syncthreads();   // all pass-1 ds reads done before overwrite
            float4 xi4 = *(const float4*)&xxb[i0 + (ty << 2)];
            float xi[4] = {xi4.x, xi4.y, xi4.z, xi4.w};
            float4 xj4 = *(const float4*)&xxb[j0 + (tx << 2)];
            float xj[4] = {xj4.x, xj4.y, xj4.z, xj4.w};
            #pragma unroll
            for (int v = 0; v < 4; ++v) {
                float4 o;
                o.x = 2.f * acc[0][v] - xj[v] - xi[0];
                o.y = 2.f * acc[1][v] - xj[v] - xi[1];
                o.z = 2.f * acc[2][v] - xj[v] - xi[2];
                o.w = 2.f * acc[3][v] - xj[v] - xi[3];
                *(float4*)&ds[(tx << 2) + v][ty << 2] = o;
            }
            __syncthreads();
            size_t prow = ((size_t)ti * (BB * NN)) + (size_t)b * NN + j0 + rrow;
            tile_select_write(ds, rrow, seg, (unsigned)i0, pk + prow * KK);
        }
    } else {
        // ================= yz GEMM path (R9 verbatim) =================
        float (*As)[68] = (float(*)[68])smem;              // [16][68]
        float (*Bs)[68] = (float(*)[68])(smem + 16 * 68);  // [16][68]
        int yb = blockIdx.x - DIST_BLOCKS;
        int oc0 = (yb >> 8) << 6;          // combined output-channel tile
        int n0 = (yb & 255) << 6;          // point tile
        float acc[4][4] = {};
        for (int k0 = 0; k0 < C; k0 += 16) {
            #pragma unroll
            for (int l = tid; l < 1024; l += 256) {
                int r = l >> 4, c = l & 15;
                int kc = k0 + c;
                As[c][r] = (kc < C) ? x[(size_t)(n0 + r) * C + kc] : 0.f;
                float bvv = 0.f;
                if (kc < C) {
                    int oc = oc0 + r;
                    int wrow = (oc < co) ? oc : (oc - co);
                    int wcol = (oc < co) ? kc : (C + kc);
                    bvv = w[(size_t)wrow * 2 * C + wcol];
                }
                Bs[c][r] = bvv;
            }
            __syncthreads();
            #pragma unroll
            for (int kk = 0; kk < 16; ++kk) {
                float4 a4 = *(const float4*)&As[kk][ty << 2];
                float4 b4 = *(const float4*)&Bs[kk][tx << 2];
                float a[4] = {a4.x, a4.y, a4.z, a4.w};
                float bv[4] = {b4.x, b4.y, b4.z, b4.w};
                #pragma unroll
                for (int u = 0; u < 4; ++u)
                    #pragma unroll
                    for (int v = 0; v < 4; ++v)
                        acc[u][v] = fmaf(a[u], bv[v], acc[u][v]);
            }
            __syncthreads();
        }
        bool isY = (oc0 < co);
        float* dst = isY ? y : z;
        int c0 = isY ? oc0 : (oc0 - co);
        #pragma unroll
        for (int u = 0; u < 4; ++u) {
            int n = n0 + (ty << 2) + u;
            float4 o;
            o.x = acc[u][0]; o.y = acc[u][1]; o.z = acc[u][2]; o.w = acc[u][3];
            *(float4*)&dst[(size_t)n * co + c0 + (tx << 2)] = o;
        }
    }
}

// ---------------- wave-parallel merge of NLIST sorted key-lists ----------------
// 2 rows per wave: lanes 0-31 = row A's 32 list heads, lanes 32-63 = row B.
__global__ __launch_bounds__(256) void topk_merge_kernel(
    const unsigned long long* __restrict__ pk, int* __restrict__ idxout) {
    int wid = threadIdx.x >> 6, lane = threadIdx.x & 63;
    int half = lane >> 5, l = lane & 31;
    int row = (blockIdx.x << 3) + (wid << 1) + half;
    size_t base = ((size_t)l * (BB * NN) + row) * KK;
    unsigned long long key = pk[base];
    int p = 0;
    int* out = idxout + (size_t)row * KK;
    for (int r = 0; r < KK; ++r) {
        unsigned long long h = key, o;
        o = __shfl_xor(h, 16); if (o > h) h = o;
        o = __shfl_xor(h, 8);  if (o > h) h = o;
        o = __shfl_xor(h, 4);  if (o > h) h = o;
        o = __shfl_xor(h, 2);  if (o > h) h = o;
        o = __shfl_xor(h, 1);  if (o > h) h = o;
        if (l == 0) out[r] = (int)(~(unsigned)h);
        if (key == h) {
            ++p;
            key = (p < KK) ? pk[base + p] : 0ull;
        }
    }
}

// ---------------- gather + max_k + BN + lrelu ----------------
__global__ void edge_apply_kernel(const float* __restrict__ y, const float* __restrict__ z,
    const int* __restrict__ idx, const float* __restrict__ g, const float* __restrict__ be,
    const float* __restrict__ rm, const float* __restrict__ rv,
    float* __restrict__ out, int co) {
    int n = blockIdx.x;   // global point id in [0, B*N)
    int o = threadIdx.x;
    int b = n >> 11;      // N = 2048
    __shared__ int sj[KK];
    if (o < KK) sj[o] = idx[(size_t)n * KK + o];
    __syncthreads();
    float yn = y[(size_t)n * co + o], zn = z[(size_t)n * co + o];
    float mx = -INFINITY, mn = INFINITY;
    #pragma unroll
    for (int j = 0; j < KK; ++j) {
        float v = y[((size_t)b * NN + sj[j]) * co + o];
        mx = fmaxf(mx, v);
        mn = fminf(mn, v);
    }
    float s = g[o] * rsqrtf(rv[o] + EPSF);
    float tt = be[o] - rm[o] * s;
    float ybest = (s >= 0.f) ? mx : mn;
    float h = fmaf(s, ybest - yn + zn, tt);
    out[(size_t)n * co + o] = (h >= 0.f) ? h : NEG_SLOPE * h;
}

// ---------------- global max over N of concat(x1..x4) ----------------
#define NSPLIT 32
__global__ void gmax_partial(const float* __restrict__ x1, const float* __restrict__ x2,
                             const float* __restrict__ x3, const float* __restrict__ x4,
                             float* __restrict__ part) {
    int ch = threadIdx.x;            // 0..511
    int split = blockIdx.x, b = blockIdx.y;
    int n0 = split * (NN / NSPLIT);
    float m = -INFINITY;
    for (int q = 0; q < NN / NSPLIT; ++q) {
        int n = b * NN + n0 + q;
        float v;
        if (ch < 64)       v = x1[(size_t)n * 64 + ch];
        else if (ch < 128) v = x2[(size_t)n * 64 + (ch - 64)];
        else if (ch < 256) v = x3[(size_t)n * 128 + (ch - 128)];
        else               v = x4[(size_t)n * 256 + (ch - 256)];
        m = fmaxf(m, v);
    }
    part[((size_t)split * BB + b) * 512 + ch] = m;
}

__global__ void gmax_final(const float* __restrict__ part, float* __restrict__ xg) {
    int ch = threadIdx.x, b = blockIdx.x;
    float m = -INFINITY;
    for (int s = 0; s < NSPLIT; ++s) m = fmaxf(m, part[((size_t)s * BB + b) * 512 + ch]);
    xg[(size_t)b * 512 + ch] = m;
}

// ---------------- final linear + BN + lrelu ----------------
__global__ void linear_kernel(const float* __restrict__ xg, const float* __restrict__ lw,
    const float* __restrict__ lb, const float* __restrict__ g5, const float* __restrict__ b5,
    const float* __restrict__ rm5, const float* __restrict__ rv5, float* __restrict__ out0) {
    int o = blockIdx.x * 256 + threadIdx.x;
    int b = blockIdx.y;
    __shared__ float xs[512];
    for (int l = threadIdx.x; l < 512; l += 256) xs[l] = xg[(size_t)b * 512 + l];
    __syncthreads();
    float acc = 0.f;
    const float* wr = lw + (size_t)o * 512;
    for (int c = 0; c < 512; ++c) acc = fmaf(xs[c], wr[c], acc);
    acc += lb[o];
    float s = g5[o] * rsqrtf(rv5[o] + EPSF);
    float h = fmaf(s, acc - rm5[o], b5[o]);
    out0[(size_t)b * 1024 + o] = (h >= 0.f) ? h : NEG_SLOPE * h;
}

// ---------------- x4 (B,N,256) -> out1 (B,256,N) ----------------
__global__ void transpose_kernel(const float* __restrict__ x4, float* __restrict__ out1) {
    __shared__ float tile[32][33];
    int b = blockIdx.z;
    int nb = blockIdx.x * 32, ob = blockIdx.y * 32;
    int tx = threadIdx.x, ty = threadIdx.y;  // (32, 8)
    #pragma unroll
    for (int r = 0; r < 4; ++r) {
        int o = ob + tx;
        int n = nb + ty + r * 8;
        tile[ty + r * 8][tx] = x4[((size_t)b * NN + n) * 256 + o];
    }
    __syncthreads();
    #pragma unroll
    for (int r = 0; r < 4; ++r) {
        int n = nb + tx;
        int o = ob + ty + r * 8;
        out1[((size_t)b * 256 + o) * NN + n] = tile[tx][ty + r * 8];
    }
}

extern "C" void kernel_launch(void* const* d_in, const int* in_sizes, int n_in,
                              void* d_out, int out_size, void* d_ws, size_t ws_size,
                              hipStream_t stream) {
    const float* x = (const float*)d_in[0];
    const float* lin_w = (const float*)d_in[21];
    const float* lin_b = (const float*)d_in[22];
    const float* g5 = (const float*)d_in[23];
    const float* b5 = (const float*)d_in[24];
    const float* rm5 = (const float*)d_in[25];
    const float* rv5 = (const float*)d_in[26];

    // ---- workspace bump allocation ----
    size_t off = 0;
    auto alloc = [&](size_t nbytes) {
        void* r = (char*)d_ws + off;
        off += (nbytes + 255) & ~(size_t)255;
        return r;
    };
    const size_t PTS = (size_t)BB * NN;
    float* xx   = (float*)alloc(PTS * 4);
    int*   idx  = (int*)  alloc(PTS * KK * 4);
    float* y    = (float*)alloc(PTS * 256 * 4);
    float* z    = (float*)alloc(PTS * 256 * 4);
    float* x1   = (float*)alloc(PTS * 64 * 4);
    float* x2   = (float*)alloc(PTS * 64 * 4);
    float* x3   = (float*)alloc(PTS * 128 * 4);
    float* x4   = (float*)alloc(PTS * 256 * 4);
    float* part = (float*)alloc((size_t)NSPLIT * BB * 512 * 4);
    float* xg   = (float*)alloc((size_t)BB * 512 * 4);
    unsigned long long* pk =
        (unsigned long long*)alloc((size_t)NLIST * PTS * KK * 8);  // per-tile top-10 keys

    const int CI[4] = {5, 64, 64, 128};
    const int CO[4] = {64, 64, 128, 256};
    const float* xin = x;
    float* xout[4] = {x1, x2, x3, x4};

    for (int l = 0; l < 4; ++l) {
        int C = CI[l], co = CO[l];
        const float* w  = (const float*)d_in[1 + l * 5 + 0];
        const float* g  = (const float*)d_in[1 + l * 5 + 1];
        const float* be = (const float*)d_in[1 + l * 5 + 2];
        const float* rm = (const float*)d_in[1 + l * 5 + 3];
        const float* rv = (const float*)d_in[1 + l * 5 + 4];

        xx_kernel<<<(BB * NN + 255) / 256, 256, 0, stream>>>(xin, xx, C);

        int yzb = (2 * co / 64) * 256;
        dim3 dgrid(DIST_BLOCKS + yzb);
        if (C == 5)
            dist_yz_kernel<5><<<dgrid, 256, 0, stream>>>(xin, xx, pk, w, y, z, co);
        else if (C == 64)
            dist_yz_kernel<64><<<dgrid, 256, 0, stream>>>(xin, xx, pk, w, y, z, co);
        else
            dist_yz_kernel<128><<<dgrid, 256, 0, stream>>>(xin, xx, pk, w, y, z, co);
        topk_merge_kernel<<<(int)(PTS / 8), 256, 0, stream>>>(pk, idx);

        edge_apply_kernel<<<(int)PTS, co, 0, stream>>>(y, z, idx, g, be, rm, rv, xout[l], co);
        xin = xout[l];
    }

    gmax_partial<<<dim3(NSPLIT, BB), 512, 0, stream>>>(x1, x2, x3, x4, part);
    gmax_final<<<BB, 512, 0, stream>>>(part, xg);
    linear_kernel<<<dim3(1024 / 256, BB), 256, 0, stream>>>(
        xg, lin_w, lin_b, g5, b5, rm5, rv5, (float*)d_out);
    transpose_kernel<<<dim3(NN / 32, 256 / 32, BB), dim3(32, 8), 0, stream>>>(
        x4, (float*)d_out + (size_t)BB * 1024);
}